// Round 1
// baseline (270.471 us; speedup 1.0000x reference)
//
#include <hip/hip_runtime.h>
#include <hip/hip_bf16.h>
#include <cstdint>
#include <cfloat>

// Problem constants
#define NTOK 16384
#define DIN  1024
#define DOUT 1024
#define NEXP 8
#define RLORA 16
#define KTOT 1152          // DIN + NEXP*RLORA
#define SCALE_LORA 2.0f    // alpha/rank = 32/16

typedef __attribute__((ext_vector_type(8))) short bf16x8;
typedef __attribute__((ext_vector_type(4))) float f32x4;

__device__ __forceinline__ unsigned short f2bf(float f) {
  __hip_bfloat16 h = __float2bfloat16(f);
  unsigned short u;
  __builtin_memcpy(&u, &h, 2);
  return u;
}

__device__ __forceinline__ void gld_lds16(const void* g, void* l) {
  __builtin_amdgcn_global_load_lds((const __attribute__((address_space(1))) void*)g,
                                   (__attribute__((address_space(3))) void*)l,
                                   16, 0, 0);
}

// ---------------------------------------------------------------------------
// Kernel 1: weight prep. WcatT[j][k] = (k<1024 ? W_base[k][j] : B[k-1024][j]) bf16
//           AcatT[jj][d] = A[jj>>4][d][jj&15] bf16
// ---------------------------------------------------------------------------
__global__ __launch_bounds__(256) void k_prep(const float* __restrict__ Wb,
                                              const float* __restrict__ A,
                                              const float* __restrict__ B,
                                              unsigned short* __restrict__ WcatT,
                                              unsigned short* __restrict__ AcatT) {
  int j = blockIdx.y;
  int k = blockIdx.x * 256 + threadIdx.x;
  if (j < 1024) {
    if (k >= KTOT) return;
    float v = (k < 1024) ? Wb[(size_t)k * 1024 + j] : B[(size_t)(k - 1024) * 1024 + j];
    WcatT[(size_t)j * KTOT + k] = f2bf(v);
  } else {
    if (k >= 1024) return;
    int jj = j - 1024;  // 0..127
    float v = A[(size_t)(jj >> 4) * 16384 + (size_t)k * 16 + (jj & 15)];
    AcatT[(size_t)jj * 1024 + k] = f2bf(v);
  }
}

// ---------------------------------------------------------------------------
// Kernel 2: router. One wave per token. fp32 logits (exact top-k), bf16 X convert.
// ---------------------------------------------------------------------------
__global__ __launch_bounds__(256) void k_router(const float* __restrict__ tokens,
                                                const float* __restrict__ Wg,
                                                float* __restrict__ out_logits,
                                                float* __restrict__ out_sel,
                                                float* __restrict__ out_w,
                                                unsigned short* __restrict__ Xcat,
                                                float4* __restrict__ gateinfo) {
  const int wid = threadIdx.x >> 6;
  const int lane = threadIdx.x & 63;
  const int t = blockIdx.x * 4 + wid;

  const float* x = tokens + (size_t)t * DIN;
  float4 xv[4];
#pragma unroll
  for (int j = 0; j < 4; ++j) xv[j] = *(const float4*)(x + j * 256 + lane * 4);

  // bf16 convert + store into Xcat cols [0,1024)
  unsigned short* xb = Xcat + (size_t)t * KTOT;
#pragma unroll
  for (int j = 0; j < 4; ++j) {
    const float* xf = (const float*)&xv[j];
    unsigned short hb[4];
#pragma unroll
    for (int m = 0; m < 4; ++m) hb[m] = f2bf(xf[m]);
    uint2 u;
    __builtin_memcpy(&u, hb, 8);
    *(uint2*)(xb + j * 256 + lane * 4) = u;
  }

  // fp32 logits: per-lane partial over 16 dims, then butterfly over 64 lanes
  float acc[8] = {0.f, 0.f, 0.f, 0.f, 0.f, 0.f, 0.f, 0.f};
#pragma unroll
  for (int j = 0; j < 4; ++j) {
    const float* xf = (const float*)&xv[j];
#pragma unroll
    for (int m = 0; m < 4; ++m) {
      int d = j * 256 + lane * 4 + m;
      float4 w0 = *(const float4*)(Wg + (size_t)d * 8);
      float4 w1 = *(const float4*)(Wg + (size_t)d * 8 + 4);
      float xs = xf[m];
      acc[0] = fmaf(xs, w0.x, acc[0]);
      acc[1] = fmaf(xs, w0.y, acc[1]);
      acc[2] = fmaf(xs, w0.z, acc[2]);
      acc[3] = fmaf(xs, w0.w, acc[3]);
      acc[4] = fmaf(xs, w1.x, acc[4]);
      acc[5] = fmaf(xs, w1.y, acc[5]);
      acc[6] = fmaf(xs, w1.z, acc[6]);
      acc[7] = fmaf(xs, w1.w, acc[7]);
    }
  }
#pragma unroll
  for (int s = 1; s < 64; s <<= 1) {
#pragma unroll
    for (int e = 0; e < 8; ++e) acc[e] += __shfl_xor(acc[e], s, 64);
  }

  // top-2 with jax tie-break (lowest index first on equal values)
  float v0 = -FLT_MAX, v1 = -FLT_MAX;
  int i0 = -1, i1 = -1;
#pragma unroll
  for (int e = 0; e < 8; ++e) {
    float v = acc[e];
    if (v > v0) { v1 = v0; i1 = i0; v0 = v; i0 = e; }
    else if (v > v1) { v1 = v; i1 = e; }
  }
  float ex = expf(v1 - v0);  // v1 <= v0
  float inv = 1.0f / (1.0f + ex);
  float w0 = inv, w1 = ex * inv;

  if (lane == 0) {
    float4* lg = (float4*)(out_logits + (size_t)t * 8);
    lg[0] = make_float4(acc[0], acc[1], acc[2], acc[3]);
    lg[1] = make_float4(acc[4], acc[5], acc[6], acc[7]);
    *(float2*)(out_sel + (size_t)t * 2) = make_float2((float)i0, (float)i1);
    *(float2*)(out_w + (size_t)t * 2) = make_float2(w0, w1);
    gateinfo[t] = make_float4((float)i0, (float)i1, w0 * SCALE_LORA, w1 * SCALE_LORA);
  }
}

// ---------------------------------------------------------------------------
// Kernel 4: apply gates: Xcat[t][1024+c] = bf16(gate * SCALE * H[t][c]) (0 off-expert)
// ---------------------------------------------------------------------------
__global__ __launch_bounds__(256) void k_gate(const float* __restrict__ H,
                                              const float4* __restrict__ gateinfo,
                                              unsigned short* __restrict__ Xcat) {
  int t = blockIdx.x * 2 + (threadIdx.x >> 7);
  int c = threadIdx.x & 127;
  float4 gi = gateinfo[t];
  int e = c >> 4;
  float h = H[(size_t)t * 128 + c];
  float v = 0.f;
  if (e == (int)gi.x) v = gi.z * h;
  else if (e == (int)gi.y) v = gi.w * h;
  Xcat[(size_t)t * KTOT + 1024 + c] = f2bf(v);
}

// ---------------------------------------------------------------------------
// GEMM: C[M x N] fp32 = A[M x K] bf16 (row-major, stride lda) @ BT[N x K] bf16
// m97 structure: global_load_lds(16B) staging, XOR-swizzled LDS slots,
// 16x16x32 bf16 MFMA, 2-barrier K-loop, BK=32, 256 threads.
// ---------------------------------------------------------------------------
template <int BM, int BN, int WM, int WN>
__global__ __launch_bounds__(256) void k_gemm(const unsigned short* __restrict__ Ag, int lda,
                                              const unsigned short* __restrict__ Bg, int ldb,
                                              float* __restrict__ C, int ldc, int KT) {
  constexpr int BK = 32;
  __shared__ alignas(16) unsigned short As[BM * BK];
  __shared__ alignas(16) unsigned short Bs[BN * BK];

  const int tid = threadIdx.x;
  const int lane = tid & 63;
  const int m0 = blockIdx.y * BM;
  const int n0 = blockIdx.x * BN;

  constexpr int WCOLS = BN / WN;  // waves along n; (BM/WM)*(BN/WN) == 4
  const int wid = tid >> 6;
  const int wm = (wid / WCOLS) * WM;
  const int wn = (wid % WCOLS) * WN;
  constexpr int MI = WM / 16, NI = WN / 16;
  constexpr int IA = (BM * BK * 2) / 4096;  // 16B issues per thread for A tile
  constexpr int IB = (BN * BK * 2) / 4096;

  f32x4 acc[MI][NI] = {};

  const int quad = lane >> 4;
  const int r16 = lane & 15;

  for (int k0 = 0; k0 < KT; k0 += BK) {
#pragma unroll
    for (int i = 0; i < IA; ++i) {
      int s = i * 256 + tid;
      int row = s >> 2;
      int q = (s & 3) ^ (row & 3);  // XOR swizzle of 16B chunks within a row
      gld_lds16(Ag + (size_t)(m0 + row) * lda + k0 + q * 8, (char*)As + s * 16);
    }
#pragma unroll
    for (int i = 0; i < IB; ++i) {
      int s = i * 256 + tid;
      int row = s >> 2;
      int q = (s & 3) ^ (row & 3);
      gld_lds16(Bg + (size_t)(n0 + row) * ldb + k0 + q * 8, (char*)Bs + s * 16);
    }
    __syncthreads();  // drains vmcnt: staging complete

    bf16x8 af[MI], bfr[NI];
#pragma unroll
    for (int mi = 0; mi < MI; ++mi) {
      int m = wm + mi * 16 + r16;
      int slot = m * 4 + (quad ^ (m & 3));
      af[mi] = *(const bf16x8*)((const char*)As + slot * 16);
    }
#pragma unroll
    for (int ni = 0; ni < NI; ++ni) {
      int n = wn + ni * 16 + r16;
      int slot = n * 4 + (quad ^ (n & 3));
      bfr[ni] = *(const bf16x8*)((const char*)Bs + slot * 16);
    }
#pragma unroll
    for (int mi = 0; mi < MI; ++mi)
#pragma unroll
      for (int ni = 0; ni < NI; ++ni)
        acc[mi][ni] = __builtin_amdgcn_mfma_f32_16x16x32_bf16(af[mi], bfr[ni], acc[mi][ni], 0, 0, 0);
    __syncthreads();  // all waves done reading LDS before next overwrite
  }

  // epilogue: C/D layout col=lane&15, row=(lane>>4)*4+reg  [m89/m91 verified]
#pragma unroll
  for (int mi = 0; mi < MI; ++mi)
#pragma unroll
    for (int ni = 0; ni < NI; ++ni)
#pragma unroll
      for (int r = 0; r < 4; ++r) {
        int row = m0 + wm + mi * 16 + quad * 4 + r;
        int cc = n0 + wn + ni * 16 + r16;
        C[(size_t)row * ldc + cc] = acc[mi][ni][r];
      }
}

// ---------------------------------------------------------------------------
extern "C" void kernel_launch(void* const* d_in, const int* in_sizes, int n_in,
                              void* d_out, int out_size, void* d_ws, size_t ws_size,
                              hipStream_t stream) {
  const float* tokens = (const float*)d_in[0];
  const float* Wb     = (const float*)d_in[1];
  const float* A      = (const float*)d_in[2];
  const float* B      = (const float*)d_in[3];
  const float* Wg     = (const float*)d_in[4];
  float* out = (float*)d_out;

  // workspace carve (all 16B aligned)
  char* ws = (char*)d_ws;
  unsigned short* Xcat  = (unsigned short*)(ws);                 // [16384][1152] bf16  37748736 B
  unsigned short* WcatT = (unsigned short*)(ws + 37748736);      // [1024][1152] bf16    2359296 B
  unsigned short* AcatT = (unsigned short*)(ws + 40108032);      // [128][1024] bf16      262144 B
  float*          H     = (float*)(ws + 40370176);               // [16384][128] f32     8388608 B
  float4*         ginfo = (float4*)(ws + 48758784);              // [16384] float4       262144 B

  // output layout: out | router_logits | selected_experts | expert_weights
  float* out_logits = out + (size_t)16384 * 1024;
  float* out_sel    = out_logits + (size_t)16384 * 8;
  float* out_w      = out_sel + (size_t)16384 * 2;

  // 1) weight prep (transposes + bf16)
  k_prep<<<dim3(5, 1152), dim3(256), 0, stream>>>(Wb, A, B, WcatT, AcatT);
  // 2) router: fp32 logits/top2/softmax + X bf16 conversion
  k_router<<<dim3(4096), dim3(256), 0, stream>>>(tokens, Wg, out_logits, out_sel, out_w, Xcat, ginfo);
  // 3) H = X @ AcatT^T  [16384 x 128], K=1024
  k_gemm<64, 128, 32, 64><<<dim3(1, 256), dim3(256), 0, stream>>>(Xcat, KTOT, AcatT, 1024, H, 128, 1024);
  // 4) Hg into Xcat cols [1024,1152)
  k_gate<<<dim3(8192), dim3(256), 0, stream>>>(H, ginfo, Xcat);
  // 5) out = Xcat @ WcatT^T  [16384 x 1024], K=1152 (base + LoRA fused)
  k_gemm<128, 128, 64, 64><<<dim3(8, 128), dim3(256), 0, stream>>>(Xcat, KTOT, WcatT, KTOT, out, 1024, KTOT);
}

// Round 2
// 246.360 us; speedup vs baseline: 1.0979x; 1.0979x over previous
//
#include <hip/hip_runtime.h>
#include <hip/hip_bf16.h>
#include <cstdint>
#include <cfloat>

#define NTOK 16384
#define DIN  1024
#define DOUT 1024
#define NEXP 8
#define RLORA 16
#define KTOT 1152          // DIN + NEXP*RLORA
#define SCALE_LORA 2.0f    // alpha/rank = 32/16

typedef __attribute__((ext_vector_type(8))) short bf16x8;
typedef __attribute__((ext_vector_type(4))) float f32x4;

__device__ __forceinline__ unsigned short f2bf(float f) {
  __hip_bfloat16 h = __float2bfloat16(f);
  unsigned short u;
  __builtin_memcpy(&u, &h, 2);
  return u;
}

__device__ __forceinline__ void gld_lds16(const void* g, void* l) {
  __builtin_amdgcn_global_load_lds((const __attribute__((address_space(1))) void*)g,
                                   (__attribute__((address_space(3))) void*)l,
                                   16, 0, 0);
}

// ---------------------------------------------------------------------------
// Transpose Wcat = [W_base; Bcat]^T -> WcatT [1024][1152] bf16, LDS-tiled.
// grid (18, 16): 64x64 tiles over (k, j). k rows 0..1023 from Wb, 1024.. from B.
// ---------------------------------------------------------------------------
__global__ __launch_bounds__(256) void k_transW(const float* __restrict__ Wb,
                                                const float* __restrict__ B,
                                                unsigned short* __restrict__ WcatT) {
  __shared__ unsigned short T[64][66];
  const int k0 = blockIdx.x * 64, j0 = blockIdx.y * 64;
  const int t = threadIdx.x;
#pragma unroll
  for (int p = 0; p < 4; ++p) {
    int kk = p * 16 + (t >> 4);
    int c4 = (t & 15) * 4;
    int k = k0 + kk;
    const float* src = (k < 1024) ? (Wb + (size_t)k * 1024) : (B + (size_t)(k - 1024) * 1024);
    float4 v = *(const float4*)(src + j0 + c4);
    T[kk][c4 + 0] = f2bf(v.x); T[kk][c4 + 1] = f2bf(v.y);
    T[kk][c4 + 2] = f2bf(v.z); T[kk][c4 + 3] = f2bf(v.w);
  }
  __syncthreads();
#pragma unroll
  for (int p = 0; p < 2; ++p) {
    int jj = p * 32 + (t >> 3);
    int kc = (t & 7) * 8;
    unsigned short buf[8];
#pragma unroll
    for (int i = 0; i < 8; ++i) buf[i] = T[kc + i][jj];
    uint4 u; __builtin_memcpy(&u, buf, 16);
    *(uint4*)(WcatT + (size_t)(j0 + jj) * KTOT + k0 + kc) = u;
  }
}

// ---------------------------------------------------------------------------
// AcatT[e*16+r][d] = A[e][d][r] bf16, LDS-tiled. grid (4, 8): (d-chunk, e).
// ---------------------------------------------------------------------------
__global__ __launch_bounds__(256) void k_transA(const float* __restrict__ A,
                                                unsigned short* __restrict__ AcatT) {
  __shared__ unsigned short T[256][17];
  const int e = blockIdx.y, d0 = blockIdx.x * 256;
  const int t = threadIdx.x;
#pragma unroll
  for (int p = 0; p < 4; ++p) {
    int idx = p * 256 + t;        // float4 index, 1024 total (256 d x 4)
    int d = idx >> 2;
    int rr = (idx & 3) * 4;
    float4 v = *(const float4*)(A + (size_t)e * 16384 + (size_t)(d0 + d) * 16 + rr);
    T[d][rr + 0] = f2bf(v.x); T[d][rr + 1] = f2bf(v.y);
    T[d][rr + 2] = f2bf(v.z); T[d][rr + 3] = f2bf(v.w);
  }
  __syncthreads();
#pragma unroll
  for (int p = 0; p < 2; ++p) {
    int slot = p * 256 + t;       // 512 slots: 16 r x 32 d-chunks
    int r = slot >> 5;
    int dc = (slot & 31) * 8;
    unsigned short buf[8];
#pragma unroll
    for (int i = 0; i < 8; ++i) buf[i] = T[dc + i][r];
    uint4 u; __builtin_memcpy(&u, buf, 16);
    *(uint4*)(AcatT + (size_t)(e * 16 + r) * 1024 + d0 + dc) = u;
  }
}

// ---------------------------------------------------------------------------
// Router: one wave per token. fp32 logits (exact top-k), bf16 X convert.
// ---------------------------------------------------------------------------
__global__ __launch_bounds__(256) void k_router(const float* __restrict__ tokens,
                                                const float* __restrict__ Wg,
                                                float* __restrict__ out_logits,
                                                float* __restrict__ out_sel,
                                                float* __restrict__ out_w,
                                                unsigned short* __restrict__ Xcat,
                                                float4* __restrict__ gateinfo) {
  const int wid = threadIdx.x >> 6;
  const int lane = threadIdx.x & 63;
  const int t = blockIdx.x * 4 + wid;

  const float* x = tokens + (size_t)t * DIN;
  float4 xv[4];
#pragma unroll
  for (int j = 0; j < 4; ++j) xv[j] = *(const float4*)(x + j * 256 + lane * 4);

  unsigned short* xb = Xcat + (size_t)t * KTOT;
#pragma unroll
  for (int j = 0; j < 4; ++j) {
    const float* xf = (const float*)&xv[j];
    unsigned short hb[4];
#pragma unroll
    for (int m = 0; m < 4; ++m) hb[m] = f2bf(xf[m]);
    uint2 u;
    __builtin_memcpy(&u, hb, 8);
    *(uint2*)(xb + j * 256 + lane * 4) = u;
  }

  float acc[8] = {0.f, 0.f, 0.f, 0.f, 0.f, 0.f, 0.f, 0.f};
#pragma unroll
  for (int j = 0; j < 4; ++j) {
    const float* xf = (const float*)&xv[j];
#pragma unroll
    for (int m = 0; m < 4; ++m) {
      int d = j * 256 + lane * 4 + m;
      float4 w0 = *(const float4*)(Wg + (size_t)d * 8);
      float4 w1 = *(const float4*)(Wg + (size_t)d * 8 + 4);
      float xs = xf[m];
      acc[0] = fmaf(xs, w0.x, acc[0]);
      acc[1] = fmaf(xs, w0.y, acc[1]);
      acc[2] = fmaf(xs, w0.z, acc[2]);
      acc[3] = fmaf(xs, w0.w, acc[3]);
      acc[4] = fmaf(xs, w1.x, acc[4]);
      acc[5] = fmaf(xs, w1.y, acc[5]);
      acc[6] = fmaf(xs, w1.z, acc[6]);
      acc[7] = fmaf(xs, w1.w, acc[7]);
    }
  }
#pragma unroll
  for (int s = 1; s < 64; s <<= 1) {
#pragma unroll
    for (int e = 0; e < 8; ++e) acc[e] += __shfl_xor(acc[e], s, 64);
  }

  float v0 = -FLT_MAX, v1 = -FLT_MAX;
  int i0 = -1, i1 = -1;
#pragma unroll
  for (int e = 0; e < 8; ++e) {
    float v = acc[e];
    if (v > v0) { v1 = v0; i1 = i0; v0 = v; i0 = e; }
    else if (v > v1) { v1 = v; i1 = e; }
  }
  float ex = expf(v1 - v0);
  float inv = 1.0f / (1.0f + ex);
  float w0 = inv, w1 = ex * inv;

  if (lane == 0) {
    float4* lg = (float4*)(out_logits + (size_t)t * 8);
    lg[0] = make_float4(acc[0], acc[1], acc[2], acc[3]);
    lg[1] = make_float4(acc[4], acc[5], acc[6], acc[7]);
    *(float2*)(out_sel + (size_t)t * 2) = make_float2((float)i0, (float)i1);
    *(float2*)(out_w + (size_t)t * 2) = make_float2(w0, w1);
    gateinfo[t] = make_float4((float)i0, (float)i1, w0 * SCALE_LORA, w1 * SCALE_LORA);
  }
}

// ---------------------------------------------------------------------------
// H-GEMM fused with gating: H = X[:, :1024] @ AcatT^T, then
// Xcat[t][1024+c] = bf16(gate_scaled * H[t][c]) written directly.
// BM=64, BN=128, BK=32, 256 threads, 4 waves of WM=32 x WN=64. grid(256).
// ---------------------------------------------------------------------------
__global__ __launch_bounds__(256) void k_hgemm(const unsigned short* __restrict__ Xg,
                                               const unsigned short* __restrict__ Ag,
                                               const float4* __restrict__ gateinfo,
                                               unsigned short* __restrict__ Xout) {
  constexpr int BK = 32;
  __shared__ alignas(16) unsigned short As[64 * BK];
  __shared__ alignas(16) unsigned short Bs[128 * BK];
  const int tid = threadIdx.x;
  const int lane = tid & 63;
  const int wid = tid >> 6;
  const int m0 = blockIdx.x * 64;
  const int wm = (wid >> 1) * 32, wn = (wid & 1) * 64;
  const int quad = lane >> 4, r16 = lane & 15;

  f32x4 acc[2][4] = {};

  for (int k0 = 0; k0 < 1024; k0 += BK) {
    {
      int s = tid;                       // A: 64 rows x 4 chunks = 256
      int r = s >> 2, p = s & 3;
      int q = p ^ ((r >> 1) & 3);
      gld_lds16(Xg + (size_t)(m0 + r) * KTOT + k0 + q * 8, (char*)As + s * 16);
    }
#pragma unroll
    for (int i = 0; i < 2; ++i) {        // B: 128 rows x 4 chunks = 512
      int s = i * 256 + tid;
      int r = s >> 2, p = s & 3;
      int q = p ^ ((r >> 1) & 3);
      gld_lds16(Ag + (size_t)r * 1024 + k0 + q * 8, (char*)Bs + s * 16);
    }
    __syncthreads();

    bf16x8 af[2], bfr[4];
#pragma unroll
    for (int mi = 0; mi < 2; ++mi) {
      int m = wm + mi * 16 + r16;
      int p = quad ^ ((m >> 1) & 3);
      af[mi] = *(const bf16x8*)((const char*)As + (m * 4 + p) * 16);
    }
#pragma unroll
    for (int ni = 0; ni < 4; ++ni) {
      int n = wn + ni * 16 + r16;
      int p = quad ^ ((n >> 1) & 3);
      bfr[ni] = *(const bf16x8*)((const char*)Bs + (n * 4 + p) * 16);
    }
#pragma unroll
    for (int mi = 0; mi < 2; ++mi)
#pragma unroll
      for (int ni = 0; ni < 4; ++ni)
        acc[mi][ni] = __builtin_amdgcn_mfma_f32_16x16x32_bf16(af[mi], bfr[ni], acc[mi][ni], 0, 0, 0);
    __syncthreads();
  }

  // gated epilogue: col c -> expert e = c>>4; write bf16 into Xcat[row][1024+c]
#pragma unroll
  for (int mi = 0; mi < 2; ++mi)
#pragma unroll
    for (int r = 0; r < 4; ++r) {
      int row = m0 + wm + mi * 16 + quad * 4 + r;
      float4 gi = gateinfo[row];
      int ie0 = (int)gi.x, ie1 = (int)gi.y;
#pragma unroll
      for (int ni = 0; ni < 4; ++ni) {
        int c = wn + ni * 16 + r16;
        int e = c >> 4;
        float h = acc[mi][ni][r];
        float v = (e == ie0) ? gi.z * h : ((e == ie1) ? gi.w * h : 0.f);
        Xout[(size_t)row * KTOT + 1024 + c] = f2bf(v);
      }
    }
}

// ---------------------------------------------------------------------------
// Main GEMM: out[16384][1024] = Xcat[16384][1152] @ WcatT[1024][1152]^T
// BM=BN=128, BK=32, 4 waves of 64x64. XCD-aware block map. grid(1024).
// ---------------------------------------------------------------------------
__global__ __launch_bounds__(256) void k_gemm_main(const unsigned short* __restrict__ Xg,
                                                   const unsigned short* __restrict__ Wg,
                                                   float* __restrict__ C) {
  constexpr int BK = 32;
  __shared__ alignas(16) unsigned short As[128 * BK];
  __shared__ alignas(16) unsigned short Bs[128 * BK];
  const int tid = threadIdx.x;
  const int lane = tid & 63;
  const int wid = tid >> 6;
  // XCD-aware map: xcd = id&7 gets 16 contiguous m-panels (A working set 4.7 MB/XCD)
  const int id = blockIdx.x;
  const int xcd = id & 7, s5 = id >> 3;
  const int m0 = (xcd * 16 + (s5 & 15)) * 128;
  const int n0 = (s5 >> 4) * 128;
  const int wm = (wid >> 1) * 64, wn = (wid & 1) * 64;
  const int quad = lane >> 4, r16 = lane & 15;

  f32x4 acc[4][4] = {};

  for (int k0 = 0; k0 < KTOT; k0 += BK) {
#pragma unroll
    for (int i = 0; i < 2; ++i) {
      int s = i * 256 + tid;
      int r = s >> 2, p = s & 3;
      int q = p ^ ((r >> 1) & 3);   // conflict-free swizzle: addr%128 distinct per 8-lane group
      gld_lds16(Xg + (size_t)(m0 + r) * KTOT + k0 + q * 8, (char*)As + s * 16);
    }
#pragma unroll
    for (int i = 0; i < 2; ++i) {
      int s = i * 256 + tid;
      int r = s >> 2, p = s & 3;
      int q = p ^ ((r >> 1) & 3);
      gld_lds16(Wg + (size_t)(n0 + r) * KTOT + k0 + q * 8, (char*)Bs + s * 16);
    }
    __syncthreads();

    bf16x8 af[4], bfr[4];
#pragma unroll
    for (int mi = 0; mi < 4; ++mi) {
      int m = wm + mi * 16 + r16;
      int p = quad ^ ((m >> 1) & 3);
      af[mi] = *(const bf16x8*)((const char*)As + (m * 4 + p) * 16);
    }
#pragma unroll
    for (int ni = 0; ni < 4; ++ni) {
      int n = wn + ni * 16 + r16;
      int p = quad ^ ((n >> 1) & 3);
      bfr[ni] = *(const bf16x8*)((const char*)Bs + (n * 4 + p) * 16);
    }
#pragma unroll
    for (int mi = 0; mi < 4; ++mi)
#pragma unroll
      for (int ni = 0; ni < 4; ++ni)
        acc[mi][ni] = __builtin_amdgcn_mfma_f32_16x16x32_bf16(af[mi], bfr[ni], acc[mi][ni], 0, 0, 0);
    __syncthreads();
  }

  // C/D layout: col = lane&15, row = quad*4 + reg  [m89/m91]
#pragma unroll
  for (int mi = 0; mi < 4; ++mi)
#pragma unroll
    for (int ni = 0; ni < 4; ++ni)
#pragma unroll
      for (int r = 0; r < 4; ++r) {
        int row = m0 + wm + mi * 16 + quad * 4 + r;
        int cc = n0 + wn + ni * 16 + r16;
        C[(size_t)row * 1024 + cc] = acc[mi][ni][r];
      }
}

// ---------------------------------------------------------------------------
extern "C" void kernel_launch(void* const* d_in, const int* in_sizes, int n_in,
                              void* d_out, int out_size, void* d_ws, size_t ws_size,
                              hipStream_t stream) {
  const float* tokens = (const float*)d_in[0];
  const float* Wb     = (const float*)d_in[1];
  const float* A      = (const float*)d_in[2];
  const float* B      = (const float*)d_in[3];
  const float* Wg     = (const float*)d_in[4];
  float* out = (float*)d_out;

  char* ws = (char*)d_ws;
  unsigned short* Xcat  = (unsigned short*)(ws);                 // [16384][1152] bf16  37748736 B
  unsigned short* WcatT = (unsigned short*)(ws + 37748736);      // [1024][1152] bf16    2359296 B
  unsigned short* AcatT = (unsigned short*)(ws + 40108032);      // [128][1024] bf16      262144 B
  float4*         ginfo = (float4*)(ws + 40370176);              // [16384] float4       262144 B

  float* out_logits = out + (size_t)16384 * 1024;
  float* out_sel    = out_logits + (size_t)16384 * 8;
  float* out_w      = out_sel + (size_t)16384 * 2;

  // 1) weight transposes (LDS-tiled, coalesced both sides)
  k_transW<<<dim3(18, 16), dim3(256), 0, stream>>>(Wb, B, WcatT);
  k_transA<<<dim3(4, 8), dim3(256), 0, stream>>>(A, AcatT);
  // 2) router: fp32 logits/top2/softmax + X bf16 conversion
  k_router<<<dim3(4096), dim3(256), 0, stream>>>(tokens, Wg, out_logits, out_sel, out_w, Xcat, ginfo);
  // 3) H-GEMM + gate fused: writes Xcat cols [1024,1152) directly
  k_hgemm<<<dim3(256), dim3(256), 0, stream>>>(Xcat, AcatT, ginfo, Xcat);
  // 4) out = Xcat @ WcatT^T, K=1152 (base + LoRA folded)
  k_gemm_main<<<dim3(1024), dim3(256), 0, stream>>>(Xcat, WcatT, out);
}

// Round 3
// 211.223 us; speedup vs baseline: 1.2805x; 1.1663x over previous
//
#include <hip/hip_runtime.h>
#include <hip/hip_bf16.h>
#include <cstdint>
#include <cfloat>

#define NTOK 16384
#define DIN  1024
#define DOUT 1024
#define NEXP 8
#define RLORA 16
#define KTOT 1152          // DIN + NEXP*RLORA
#define SCALE_LORA 2.0f    // alpha/rank = 32/16

typedef __attribute__((ext_vector_type(8))) short bf16x8;
typedef __attribute__((ext_vector_type(4))) float f32x4;

__device__ __forceinline__ unsigned short f2bf(float f) {
  __hip_bfloat16 h = __float2bfloat16(f);
  unsigned short u;
  __builtin_memcpy(&u, &h, 2);
  return u;
}

__device__ __forceinline__ void gld_lds16(const void* g, void* l) {
  __builtin_amdgcn_global_load_lds((const __attribute__((address_space(1))) void*)g,
                                   (__attribute__((address_space(3))) void*)l,
                                   16, 0, 0);
}

// ---------------------------------------------------------------------------
// Transpose Wcat = [W_base; Bcat]^T -> WcatT [1024][1152] bf16, LDS-tiled.
// ---------------------------------------------------------------------------
__global__ __launch_bounds__(256) void k_transW(const float* __restrict__ Wb,
                                                const float* __restrict__ B,
                                                unsigned short* __restrict__ WcatT) {
  __shared__ unsigned short T[64][66];
  const int k0 = blockIdx.x * 64, j0 = blockIdx.y * 64;
  const int t = threadIdx.x;
#pragma unroll
  for (int p = 0; p < 4; ++p) {
    int kk = p * 16 + (t >> 4);
    int c4 = (t & 15) * 4;
    int k = k0 + kk;
    const float* src = (k < 1024) ? (Wb + (size_t)k * 1024) : (B + (size_t)(k - 1024) * 1024);
    float4 v = *(const float4*)(src + j0 + c4);
    T[kk][c4 + 0] = f2bf(v.x); T[kk][c4 + 1] = f2bf(v.y);
    T[kk][c4 + 2] = f2bf(v.z); T[kk][c4 + 3] = f2bf(v.w);
  }
  __syncthreads();
#pragma unroll
  for (int p = 0; p < 2; ++p) {
    int jj = p * 32 + (t >> 3);
    int kc = (t & 7) * 8;
    unsigned short buf[8];
#pragma unroll
    for (int i = 0; i < 8; ++i) buf[i] = T[kc + i][jj];
    uint4 u; __builtin_memcpy(&u, buf, 16);
    *(uint4*)(WcatT + (size_t)(j0 + jj) * KTOT + k0 + kc) = u;
  }
}

// ---------------------------------------------------------------------------
// AcatT[e*16+r][d] = A[e][d][r] bf16, LDS-tiled. grid (4, 8): (d-chunk, e).
// ---------------------------------------------------------------------------
__global__ __launch_bounds__(256) void k_transA(const float* __restrict__ A,
                                                unsigned short* __restrict__ AcatT) {
  __shared__ unsigned short T[256][17];
  const int e = blockIdx.y, d0 = blockIdx.x * 256;
  const int t = threadIdx.x;
#pragma unroll
  for (int p = 0; p < 4; ++p) {
    int idx = p * 256 + t;
    int d = idx >> 2;
    int rr = (idx & 3) * 4;
    float4 v = *(const float4*)(A + (size_t)e * 16384 + (size_t)(d0 + d) * 16 + rr);
    T[d][rr + 0] = f2bf(v.x); T[d][rr + 1] = f2bf(v.y);
    T[d][rr + 2] = f2bf(v.z); T[d][rr + 3] = f2bf(v.w);
  }
  __syncthreads();
#pragma unroll
  for (int p = 0; p < 2; ++p) {
    int slot = p * 256 + t;
    int r = slot >> 5;
    int dc = (slot & 31) * 8;
    unsigned short buf[8];
#pragma unroll
    for (int i = 0; i < 8; ++i) buf[i] = T[dc + i][r];
    uint4 u; __builtin_memcpy(&u, buf, 16);
    *(uint4*)(AcatT + (size_t)(e * 16 + r) * 1024 + d0 + dc) = u;
  }
}

// ---------------------------------------------------------------------------
// WgT[e][d] = Wg[d][e] fp32 (32 KB). grid(4), block(256): thread t -> d.
// ---------------------------------------------------------------------------
__global__ __launch_bounds__(256) void k_transG(const float* __restrict__ Wg,
                                                float* __restrict__ WgT) {
  int d = blockIdx.x * 256 + threadIdx.x;
  float4 a = *(const float4*)(Wg + (size_t)d * 8);
  float4 b = *(const float4*)(Wg + (size_t)d * 8 + 4);
  WgT[0 * 1024 + d] = a.x; WgT[1 * 1024 + d] = a.y;
  WgT[2 * 1024 + d] = a.z; WgT[3 * 1024 + d] = a.w;
  WgT[4 * 1024 + d] = b.x; WgT[5 * 1024 + d] = b.y;
  WgT[6 * 1024 + d] = b.z; WgT[7 * 1024 + d] = b.w;
}

// ---------------------------------------------------------------------------
// Router: one wave per token. Coalesced WgT loads (lane-contiguous, L1-hot).
// ---------------------------------------------------------------------------
__global__ __launch_bounds__(256) void k_router(const float* __restrict__ tokens,
                                                const float* __restrict__ WgT,
                                                float* __restrict__ out_logits,
                                                float* __restrict__ out_sel,
                                                float* __restrict__ out_w,
                                                unsigned short* __restrict__ Xcat,
                                                float4* __restrict__ gateinfo) {
  const int wid = threadIdx.x >> 6;
  const int lane = threadIdx.x & 63;
  const int t = blockIdx.x * 4 + wid;

  const float* x = tokens + (size_t)t * DIN;
  float4 xv[4];
#pragma unroll
  for (int j = 0; j < 4; ++j) xv[j] = *(const float4*)(x + j * 256 + lane * 4);

  unsigned short* xb = Xcat + (size_t)t * KTOT;
#pragma unroll
  for (int j = 0; j < 4; ++j) {
    const float* xf = (const float*)&xv[j];
    unsigned short hb[4];
#pragma unroll
    for (int m = 0; m < 4; ++m) hb[m] = f2bf(xf[m]);
    uint2 u;
    __builtin_memcpy(&u, hb, 8);
    *(uint2*)(xb + j * 256 + lane * 4) = u;
  }

  float acc[8] = {0.f, 0.f, 0.f, 0.f, 0.f, 0.f, 0.f, 0.f};
#pragma unroll
  for (int j = 0; j < 4; ++j) {
#pragma unroll
    for (int e = 0; e < 8; ++e) {
      float4 wv = *(const float4*)(WgT + (size_t)e * 1024 + j * 256 + lane * 4);
      acc[e] = fmaf(xv[j].x, wv.x,
               fmaf(xv[j].y, wv.y,
               fmaf(xv[j].z, wv.z,
               fmaf(xv[j].w, wv.w, acc[e]))));
    }
  }
#pragma unroll
  for (int s = 1; s < 64; s <<= 1) {
#pragma unroll
    for (int e = 0; e < 8; ++e) acc[e] += __shfl_xor(acc[e], s, 64);
  }

  float v0 = -FLT_MAX, v1 = -FLT_MAX;
  int i0 = -1, i1 = -1;
#pragma unroll
  for (int e = 0; e < 8; ++e) {
    float v = acc[e];
    if (v > v0) { v1 = v0; i1 = i0; v0 = v; i0 = e; }
    else if (v > v1) { v1 = v; i1 = e; }
  }
  float ex = expf(v1 - v0);
  float inv = 1.0f / (1.0f + ex);
  float w0 = inv, w1 = ex * inv;

  if (lane == 0) {
    float4* lg = (float4*)(out_logits + (size_t)t * 8);
    lg[0] = make_float4(acc[0], acc[1], acc[2], acc[3]);
    lg[1] = make_float4(acc[4], acc[5], acc[6], acc[7]);
    *(float2*)(out_sel + (size_t)t * 2) = make_float2((float)i0, (float)i1);
    *(float2*)(out_w + (size_t)t * 2) = make_float2(w0, w1);
    gateinfo[t] = make_float4((float)i0, (float)i1, w0 * SCALE_LORA, w1 * SCALE_LORA);
  }
}

// ---------------------------------------------------------------------------
// H-GEMM fused with gating. BM=64, BN=64, BK=32, 4 waves of 32x32. grid(512).
// XCD map: co-resident blocks share the m-panel (A footprint 2.4 MB/XCD).
// ---------------------------------------------------------------------------
__global__ __launch_bounds__(256) void k_hgemm(const unsigned short* __restrict__ Xg,
                                               const unsigned short* __restrict__ Ag,
                                               const float4* __restrict__ gateinfo,
                                               unsigned short* __restrict__ Xout) {
  constexpr int BK = 32;
  __shared__ alignas(16) unsigned short As[64 * BK];
  __shared__ alignas(16) unsigned short Bs[64 * BK];
  const int tid = threadIdx.x;
  const int lane = tid & 63;
  const int wid = tid >> 6;
  const int id = blockIdx.x;
  const int xcd = id & 7, s5 = id >> 3;      // s5 in [0,64)
  const int n0 = (s5 & 1) * 64;              // co-resident blocks share m
  const int m0 = (xcd * 32 + (s5 >> 1)) * 64;
  const int wm = (wid >> 1) * 32, wn = (wid & 1) * 32;
  const int quad = lane >> 4, r16 = lane & 15;

  f32x4 acc[2][2] = {};

  for (int k0 = 0; k0 < 1024; k0 += BK) {
    {
      int s = tid;                           // A: 64 rows x 4 chunks
      int r = s >> 2, p = s & 3;
      int q = p ^ ((r >> 1) & 3);
      gld_lds16(Xg + (size_t)(m0 + r) * KTOT + k0 + q * 8, (char*)As + s * 16);
    }
    {
      int s = tid;                           // B: 64 rows x 4 chunks
      int r = s >> 2, p = s & 3;
      int q = p ^ ((r >> 1) & 3);
      gld_lds16(Ag + (size_t)(n0 + r) * 1024 + k0 + q * 8, (char*)Bs + s * 16);
    }
    __syncthreads();

    bf16x8 af[2], bfr[2];
#pragma unroll
    for (int mi = 0; mi < 2; ++mi) {
      int m = wm + mi * 16 + r16;
      int p = quad ^ ((m >> 1) & 3);
      af[mi] = *(const bf16x8*)((const char*)As + (m * 4 + p) * 16);
    }
#pragma unroll
    for (int ni = 0; ni < 2; ++ni) {
      int n = wn + ni * 16 + r16;
      int p = quad ^ ((n >> 1) & 3);
      bfr[ni] = *(const bf16x8*)((const char*)Bs + (n * 4 + p) * 16);
    }
#pragma unroll
    for (int mi = 0; mi < 2; ++mi)
#pragma unroll
      for (int ni = 0; ni < 2; ++ni)
        acc[mi][ni] = __builtin_amdgcn_mfma_f32_16x16x32_bf16(af[mi], bfr[ni], acc[mi][ni], 0, 0, 0);
    __syncthreads();
  }

  // gated epilogue -> Xcat[row][1024 + n0 + c]
#pragma unroll
  for (int mi = 0; mi < 2; ++mi)
#pragma unroll
    for (int r = 0; r < 4; ++r) {
      int row = m0 + wm + mi * 16 + quad * 4 + r;
      float4 gi = gateinfo[row];
      int ie0 = (int)gi.x, ie1 = (int)gi.y;
#pragma unroll
      for (int ni = 0; ni < 2; ++ni) {
        int c = n0 + wn + ni * 16 + r16;
        int e = c >> 4;
        float h = acc[mi][ni][r];
        float v = (e == ie0) ? gi.z * h : ((e == ie1) ? gi.w * h : 0.f);
        Xout[(size_t)row * KTOT + 1024 + c] = f2bf(v);
      }
    }
}

// ---------------------------------------------------------------------------
// Main GEMM: out = Xcat @ WcatT^T. BM=BN=128, BK=32, 4 waves of 64x64.
// XCD map: co-resident blocks share the m-panel (A 1.2 MB + WcatT 2.25 MB < L2).
// ---------------------------------------------------------------------------
__global__ __launch_bounds__(256) void k_gemm_main(const unsigned short* __restrict__ Xg,
                                                   const unsigned short* __restrict__ Wg,
                                                   float* __restrict__ C) {
  constexpr int BK = 32;
  __shared__ alignas(16) unsigned short As[128 * BK];
  __shared__ alignas(16) unsigned short Bs[128 * BK];
  const int tid = threadIdx.x;
  const int lane = tid & 63;
  const int wid = tid >> 6;
  const int id = blockIdx.x;
  const int xcd = id & 7, s5 = id >> 3;      // s5 in [0,128)
  const int n0 = (s5 & 7) * 128;             // co-resident blocks share m
  const int m0 = (xcd * 16 + (s5 >> 3)) * 128;
  const int wm = (wid >> 1) * 64, wn = (wid & 1) * 64;
  const int quad = lane >> 4, r16 = lane & 15;

  f32x4 acc[4][4] = {};

  for (int k0 = 0; k0 < KTOT; k0 += BK) {
#pragma unroll
    for (int i = 0; i < 2; ++i) {
      int s = i * 256 + tid;
      int r = s >> 2, p = s & 3;
      int q = p ^ ((r >> 1) & 3);   // conflict-free: addr%128 distinct per 8-lane group
      gld_lds16(Xg + (size_t)(m0 + r) * KTOT + k0 + q * 8, (char*)As + s * 16);
    }
#pragma unroll
    for (int i = 0; i < 2; ++i) {
      int s = i * 256 + tid;
      int r = s >> 2, p = s & 3;
      int q = p ^ ((r >> 1) & 3);
      gld_lds16(Wg + (size_t)(n0 + r) * KTOT + k0 + q * 8, (char*)Bs + s * 16);
    }
    __syncthreads();

    bf16x8 af[4], bfr[4];
#pragma unroll
    for (int mi = 0; mi < 4; ++mi) {
      int m = wm + mi * 16 + r16;
      int p = quad ^ ((m >> 1) & 3);
      af[mi] = *(const bf16x8*)((const char*)As + (m * 4 + p) * 16);
    }
#pragma unroll
    for (int ni = 0; ni < 4; ++ni) {
      int n = wn + ni * 16 + r16;
      int p = quad ^ ((n >> 1) & 3);
      bfr[ni] = *(const bf16x8*)((const char*)Bs + (n * 4 + p) * 16);
    }
#pragma unroll
    for (int mi = 0; mi < 4; ++mi)
#pragma unroll
      for (int ni = 0; ni < 4; ++ni)
        acc[mi][ni] = __builtin_amdgcn_mfma_f32_16x16x32_bf16(af[mi], bfr[ni], acc[mi][ni], 0, 0, 0);
    __syncthreads();
  }

  // C/D layout: col = lane&15, row = quad*4 + reg  [m89/m91]
#pragma unroll
  for (int mi = 0; mi < 4; ++mi)
#pragma unroll
    for (int ni = 0; ni < 4; ++ni)
#pragma unroll
      for (int r = 0; r < 4; ++r) {
        int row = m0 + wm + mi * 16 + quad * 4 + r;
        int cc = n0 + wn + ni * 16 + r16;
        C[(size_t)row * 1024 + cc] = acc[mi][ni][r];
      }
}

// ---------------------------------------------------------------------------
extern "C" void kernel_launch(void* const* d_in, const int* in_sizes, int n_in,
                              void* d_out, int out_size, void* d_ws, size_t ws_size,
                              hipStream_t stream) {
  const float* tokens = (const float*)d_in[0];
  const float* Wb     = (const float*)d_in[1];
  const float* A      = (const float*)d_in[2];
  const float* B      = (const float*)d_in[3];
  const float* Wg     = (const float*)d_in[4];
  float* out = (float*)d_out;

  char* ws = (char*)d_ws;
  unsigned short* Xcat  = (unsigned short*)(ws);                 // [16384][1152] bf16  37748736 B
  unsigned short* WcatT = (unsigned short*)(ws + 37748736);      // [1024][1152] bf16    2359296 B
  unsigned short* AcatT = (unsigned short*)(ws + 40108032);      // [128][1024] bf16      262144 B
  float4*         ginfo = (float4*)(ws + 40370176);              // [16384] float4       262144 B
  float*          WgT   = (float*)(ws + 40632320);               // [8][1024] fp32         32768 B

  float* out_logits = out + (size_t)16384 * 1024;
  float* out_sel    = out_logits + (size_t)16384 * 8;
  float* out_w      = out_sel + (size_t)16384 * 2;

  k_transW<<<dim3(18, 16), dim3(256), 0, stream>>>(Wb, B, WcatT);
  k_transA<<<dim3(4, 8), dim3(256), 0, stream>>>(A, AcatT);
  k_transG<<<dim3(4), dim3(256), 0, stream>>>(Wg, WgT);
  k_router<<<dim3(4096), dim3(256), 0, stream>>>(tokens, WgT, out_logits, out_sel, out_w, Xcat, ginfo);
  k_hgemm<<<dim3(512), dim3(256), 0, stream>>>(Xcat, AcatT, ginfo, Xcat);
  k_gemm_main<<<dim3(1024), dim3(256), 0, stream>>>(Xcat, WcatT, out);
}

// Round 4
// 193.186 us; speedup vs baseline: 1.4001x; 1.0934x over previous
//
#include <hip/hip_runtime.h>
#include <hip/hip_bf16.h>
#include <cstdint>
#include <cfloat>

#define NTOK 16384
#define DIN  1024
#define DOUT 1024
#define NEXP 8
#define RLORA 16
#define KTOT 1152          // DIN + NEXP*RLORA
#define SCALE_LORA 2.0f    // alpha/rank = 32/16

typedef __attribute__((ext_vector_type(8))) short bf16x8;
typedef __attribute__((ext_vector_type(4))) float f32x4;

__device__ __forceinline__ unsigned short f2bf(float f) {
  __hip_bfloat16 h = __float2bfloat16(f);
  unsigned short u;
  __builtin_memcpy(&u, &h, 2);
  return u;
}

__device__ __forceinline__ void gld_lds16(const void* g, void* l) {
  __builtin_amdgcn_global_load_lds((const __attribute__((address_space(1))) void*)g,
                                   (__attribute__((address_space(3))) void*)l,
                                   16, 0, 0);
}

// ---------------------------------------------------------------------------
// Transpose Wcat = [W_base; Bcat]^T -> WcatT [1024][1152] bf16, LDS-tiled.
// ---------------------------------------------------------------------------
__global__ __launch_bounds__(256) void k_transW(const float* __restrict__ Wb,
                                                const float* __restrict__ B,
                                                unsigned short* __restrict__ WcatT) {
  __shared__ unsigned short T[64][66];
  const int k0 = blockIdx.x * 64, j0 = blockIdx.y * 64;
  const int t = threadIdx.x;
#pragma unroll
  for (int p = 0; p < 4; ++p) {
    int kk = p * 16 + (t >> 4);
    int c4 = (t & 15) * 4;
    int k = k0 + kk;
    const float* src = (k < 1024) ? (Wb + (size_t)k * 1024) : (B + (size_t)(k - 1024) * 1024);
    float4 v = *(const float4*)(src + j0 + c4);
    T[kk][c4 + 0] = f2bf(v.x); T[kk][c4 + 1] = f2bf(v.y);
    T[kk][c4 + 2] = f2bf(v.z); T[kk][c4 + 3] = f2bf(v.w);
  }
  __syncthreads();
#pragma unroll
  for (int p = 0; p < 2; ++p) {
    int jj = p * 32 + (t >> 3);
    int kc = (t & 7) * 8;
    unsigned short buf[8];
#pragma unroll
    for (int i = 0; i < 8; ++i) buf[i] = T[kc + i][jj];
    uint4 u; __builtin_memcpy(&u, buf, 16);
    *(uint4*)(WcatT + (size_t)(j0 + jj) * KTOT + k0 + kc) = u;
  }
}

// ---------------------------------------------------------------------------
// AcatT[e*16+r][d] = A[e][d][r] bf16, LDS-tiled. grid (4, 8): (d-chunk, e).
// ---------------------------------------------------------------------------
__global__ __launch_bounds__(256) void k_transA(const float* __restrict__ A,
                                                unsigned short* __restrict__ AcatT) {
  __shared__ unsigned short T[256][17];
  const int e = blockIdx.y, d0 = blockIdx.x * 256;
  const int t = threadIdx.x;
#pragma unroll
  for (int p = 0; p < 4; ++p) {
    int idx = p * 256 + t;
    int d = idx >> 2;
    int rr = (idx & 3) * 4;
    float4 v = *(const float4*)(A + (size_t)e * 16384 + (size_t)(d0 + d) * 16 + rr);
    T[d][rr + 0] = f2bf(v.x); T[d][rr + 1] = f2bf(v.y);
    T[d][rr + 2] = f2bf(v.z); T[d][rr + 3] = f2bf(v.w);
  }
  __syncthreads();
#pragma unroll
  for (int p = 0; p < 2; ++p) {
    int slot = p * 256 + t;
    int r = slot >> 5;
    int dc = (slot & 31) * 8;
    unsigned short buf[8];
#pragma unroll
    for (int i = 0; i < 8; ++i) buf[i] = T[dc + i][r];
    uint4 u; __builtin_memcpy(&u, buf, 16);
    *(uint4*)(AcatT + (size_t)(e * 16 + r) * 1024 + d0 + dc) = u;
  }
}

// ---------------------------------------------------------------------------
// WgT[e][d] = Wg[d][e] fp32 (32 KB). grid(4), block(256).
// ---------------------------------------------------------------------------
__global__ __launch_bounds__(256) void k_transG(const float* __restrict__ Wg,
                                                float* __restrict__ WgT) {
  int d = blockIdx.x * 256 + threadIdx.x;
  float4 a = *(const float4*)(Wg + (size_t)d * 8);
  float4 b = *(const float4*)(Wg + (size_t)d * 8 + 4);
  WgT[0 * 1024 + d] = a.x; WgT[1 * 1024 + d] = a.y;
  WgT[2 * 1024 + d] = a.z; WgT[3 * 1024 + d] = a.w;
  WgT[4 * 1024 + d] = b.x; WgT[5 * 1024 + d] = b.y;
  WgT[6 * 1024 + d] = b.z; WgT[7 * 1024 + d] = b.w;
}

// ---------------------------------------------------------------------------
// Router: one wave per TWO tokens (ILP: WgT loads shared, two independent
// reduction chains). grid 2048.
// ---------------------------------------------------------------------------
__global__ __launch_bounds__(256) void k_router(const float* __restrict__ tokens,
                                                const float* __restrict__ WgT,
                                                float* __restrict__ out_logits,
                                                float* __restrict__ out_sel,
                                                float* __restrict__ out_w,
                                                unsigned short* __restrict__ Xcat,
                                                float4* __restrict__ gateinfo) {
  const int wid = threadIdx.x >> 6;
  const int lane = threadIdx.x & 63;
  const int t0 = (blockIdx.x * 4 + wid) * 2;

  float4 xa[4], xb[4];
  const float* x0 = tokens + (size_t)t0 * DIN;
  const float* x1 = x0 + DIN;
#pragma unroll
  for (int j = 0; j < 4; ++j) {
    xa[j] = *(const float4*)(x0 + j * 256 + lane * 4);
    xb[j] = *(const float4*)(x1 + j * 256 + lane * 4);
  }

#pragma unroll
  for (int tt = 0; tt < 2; ++tt) {
    unsigned short* xbp = Xcat + (size_t)(t0 + tt) * KTOT;
    const float4* xv = tt ? xb : xa;
#pragma unroll
    for (int j = 0; j < 4; ++j) {
      const float* xf = (const float*)&xv[j];
      unsigned short hb[4];
#pragma unroll
      for (int m = 0; m < 4; ++m) hb[m] = f2bf(xf[m]);
      uint2 u;
      __builtin_memcpy(&u, hb, 8);
      *(uint2*)(xbp + j * 256 + lane * 4) = u;
    }
  }

  float accA[8] = {0,0,0,0,0,0,0,0}, accB[8] = {0,0,0,0,0,0,0,0};
#pragma unroll
  for (int j = 0; j < 4; ++j) {
#pragma unroll
    for (int e = 0; e < 8; ++e) {
      float4 wv = *(const float4*)(WgT + (size_t)e * 1024 + j * 256 + lane * 4);
      accA[e] = fmaf(xa[j].x, wv.x, fmaf(xa[j].y, wv.y,
                fmaf(xa[j].z, wv.z, fmaf(xa[j].w, wv.w, accA[e]))));
      accB[e] = fmaf(xb[j].x, wv.x, fmaf(xb[j].y, wv.y,
                fmaf(xb[j].z, wv.z, fmaf(xb[j].w, wv.w, accB[e]))));
    }
  }
#pragma unroll
  for (int s = 1; s < 64; s <<= 1) {
#pragma unroll
    for (int e = 0; e < 8; ++e) {
      accA[e] += __shfl_xor(accA[e], s, 64);
      accB[e] += __shfl_xor(accB[e], s, 64);
    }
  }

#pragma unroll
  for (int tt = 0; tt < 2; ++tt) {
    const float* acc = tt ? accB : accA;
    int t = t0 + tt;
    float v0 = -FLT_MAX, v1 = -FLT_MAX;
    int i0 = -1, i1 = -1;
#pragma unroll
    for (int e = 0; e < 8; ++e) {
      float v = acc[e];
      if (v > v0) { v1 = v0; i1 = i0; v0 = v; i0 = e; }
      else if (v > v1) { v1 = v; i1 = e; }
    }
    float ex = expf(v1 - v0);
    float inv = 1.0f / (1.0f + ex);
    float w0 = inv, w1 = ex * inv;
    if (lane == 0) {
      float4* lg = (float4*)(out_logits + (size_t)t * 8);
      lg[0] = make_float4(acc[0], acc[1], acc[2], acc[3]);
      lg[1] = make_float4(acc[4], acc[5], acc[6], acc[7]);
      *(float2*)(out_sel + (size_t)t * 2) = make_float2((float)i0, (float)i1);
      *(float2*)(out_w + (size_t)t * 2) = make_float2(w0, w1);
      gateinfo[t] = make_float4((float)i0, (float)i1, w0 * SCALE_LORA, w1 * SCALE_LORA);
    }
  }
}

// ---------------------------------------------------------------------------
// H-GEMM + gating. BM=64, BN=64, BK=64 (h-loop keeps regs flat), grid 512.
// 8 MFMA per wave per barrier-pair (2x R3).
// ---------------------------------------------------------------------------
__global__ __launch_bounds__(256) void k_hgemm(const unsigned short* __restrict__ Xg,
                                               const unsigned short* __restrict__ Ag,
                                               const float4* __restrict__ gateinfo,
                                               unsigned short* __restrict__ Xout) {
  constexpr int BK = 64;
  __shared__ alignas(16) unsigned short As[64 * BK];
  __shared__ alignas(16) unsigned short Bs[64 * BK];
  const int tid = threadIdx.x;
  const int lane = tid & 63;
  const int wid = tid >> 6;
  const int id = blockIdx.x;
  const int xcd = id & 7, s5 = id >> 3;
  const int n0 = (s5 & 1) * 64;
  const int m0 = (xcd * 32 + (s5 >> 1)) * 64;
  const int wm = (wid >> 1) * 32, wn = (wid & 1) * 32;
  const int quad = lane >> 4, r16 = lane & 15;

  f32x4 acc[2][2] = {};

  for (int k0 = 0; k0 < 1024; k0 += BK) {
#pragma unroll
    for (int i = 0; i < 2; ++i) {          // A: 64 rows x 8 chunks = 512
      int s = i * 256 + tid;
      int r = s >> 3, c = s & 7;
      int q = c ^ ((r >> 1) & 7);
      gld_lds16(Xg + (size_t)(m0 + r) * KTOT + k0 + q * 8, (char*)As + s * 16);
    }
#pragma unroll
    for (int i = 0; i < 2; ++i) {          // B: 64 rows x 8 chunks
      int s = i * 256 + tid;
      int r = s >> 3, c = s & 7;
      int q = c ^ ((r >> 1) & 7);
      gld_lds16(Ag + (size_t)(n0 + r) * 1024 + k0 + q * 8, (char*)Bs + s * 16);
    }
    __syncthreads();

#pragma unroll
    for (int h = 0; h < 2; ++h) {
      bf16x8 af[2], bfr[2];
#pragma unroll
      for (int mi = 0; mi < 2; ++mi) {
        int m = wm + mi * 16 + r16;
        int slot = m * 8 + ((h * 4 + quad) ^ ((m >> 1) & 7));
        af[mi] = *(const bf16x8*)((const char*)As + slot * 16);
      }
#pragma unroll
      for (int ni = 0; ni < 2; ++ni) {
        int n = wn + ni * 16 + r16;
        int slot = n * 8 + ((h * 4 + quad) ^ ((n >> 1) & 7));
        bfr[ni] = *(const bf16x8*)((const char*)Bs + slot * 16);
      }
#pragma unroll
      for (int mi = 0; mi < 2; ++mi)
#pragma unroll
        for (int ni = 0; ni < 2; ++ni)
          acc[mi][ni] = __builtin_amdgcn_mfma_f32_16x16x32_bf16(af[mi], bfr[ni], acc[mi][ni], 0, 0, 0);
    }
    __syncthreads();
  }

#pragma unroll
  for (int mi = 0; mi < 2; ++mi)
#pragma unroll
    for (int r = 0; r < 4; ++r) {
      int row = m0 + wm + mi * 16 + quad * 4 + r;
      float4 gi = gateinfo[row];
      int ie0 = (int)gi.x, ie1 = (int)gi.y;
#pragma unroll
      for (int ni = 0; ni < 2; ++ni) {
        int c = n0 + wn + ni * 16 + r16;
        int e = c >> 4;
        float h = acc[mi][ni][r];
        float v = (e == ie0) ? gi.z * h : ((e == ie1) ? gi.w * h : 0.f);
        Xout[(size_t)row * KTOT + 1024 + c] = f2bf(v);
      }
    }
}

// ---------------------------------------------------------------------------
// Main GEMM: out = Xcat @ WcatT^T. BM=BN=128, BK=64 (h-loop), 4 waves 64x64.
// 32 MFMA per wave per barrier-pair (2x R3); 18 K-steps.
// ---------------------------------------------------------------------------
__global__ __launch_bounds__(256) void k_gemm_main(const unsigned short* __restrict__ Xg,
                                                   const unsigned short* __restrict__ Wg,
                                                   float* __restrict__ C) {
  constexpr int BK = 64;
  __shared__ alignas(16) unsigned short As[128 * BK];  // 16 KB
  __shared__ alignas(16) unsigned short Bs[128 * BK];  // 16 KB
  const int tid = threadIdx.x;
  const int lane = tid & 63;
  const int wid = tid >> 6;
  const int id = blockIdx.x;
  const int xcd = id & 7, s5 = id >> 3;
  const int n0 = (s5 & 7) * 128;
  const int m0 = (xcd * 16 + (s5 >> 3)) * 128;
  const int wm = (wid >> 1) * 64, wn = (wid & 1) * 64;
  const int quad = lane >> 4, r16 = lane & 15;

  f32x4 acc[4][4] = {};

  for (int k0 = 0; k0 < KTOT; k0 += BK) {
#pragma unroll
    for (int i = 0; i < 4; ++i) {          // A: 128 rows x 8 chunks = 1024
      int s = i * 256 + tid;
      int r = s >> 3, c = s & 7;
      int q = c ^ ((r >> 1) & 7);
      gld_lds16(Xg + (size_t)(m0 + r) * KTOT + k0 + q * 8, (char*)As + s * 16);
    }
#pragma unroll
    for (int i = 0; i < 4; ++i) {
      int s = i * 256 + tid;
      int r = s >> 3, c = s & 7;
      int q = c ^ ((r >> 1) & 7);
      gld_lds16(Wg + (size_t)(n0 + r) * KTOT + k0 + q * 8, (char*)Bs + s * 16);
    }
    __syncthreads();

#pragma unroll
    for (int h = 0; h < 2; ++h) {
      bf16x8 af[4], bfr[4];
#pragma unroll
      for (int mi = 0; mi < 4; ++mi) {
        int m = wm + mi * 16 + r16;
        int slot = m * 8 + ((h * 4 + quad) ^ ((m >> 1) & 7));
        af[mi] = *(const bf16x8*)((const char*)As + slot * 16);
      }
#pragma unroll
      for (int ni = 0; ni < 4; ++ni) {
        int n = wn + ni * 16 + r16;
        int slot = n * 8 + ((h * 4 + quad) ^ ((n >> 1) & 7));
        bfr[ni] = *(const bf16x8*)((const char*)Bs + slot * 16);
      }
#pragma unroll
      for (int mi = 0; mi < 4; ++mi)
#pragma unroll
        for (int ni = 0; ni < 4; ++ni)
          acc[mi][ni] = __builtin_amdgcn_mfma_f32_16x16x32_bf16(af[mi], bfr[ni], acc[mi][ni], 0, 0, 0);
    }
    __syncthreads();
  }

  // C/D layout: col = lane&15, row = quad*4 + reg  [m89/m91]
#pragma unroll
  for (int mi = 0; mi < 4; ++mi)
#pragma unroll
    for (int ni = 0; ni < 4; ++ni)
#pragma unroll
      for (int r = 0; r < 4; ++r) {
        int row = m0 + wm + mi * 16 + quad * 4 + r;
        int cc = n0 + wn + ni * 16 + r16;
        C[(size_t)row * 1024 + cc] = acc[mi][ni][r];
      }
}

// ---------------------------------------------------------------------------
extern "C" void kernel_launch(void* const* d_in, const int* in_sizes, int n_in,
                              void* d_out, int out_size, void* d_ws, size_t ws_size,
                              hipStream_t stream) {
  const float* tokens = (const float*)d_in[0];
  const float* Wb     = (const float*)d_in[1];
  const float* A      = (const float*)d_in[2];
  const float* B      = (const float*)d_in[3];
  const float* Wg     = (const float*)d_in[4];
  float* out = (float*)d_out;

  char* ws = (char*)d_ws;
  unsigned short* Xcat  = (unsigned short*)(ws);                 // [16384][1152] bf16  37748736 B
  unsigned short* WcatT = (unsigned short*)(ws + 37748736);      // [1024][1152] bf16    2359296 B
  unsigned short* AcatT = (unsigned short*)(ws + 40108032);      // [128][1024] bf16      262144 B
  float4*         ginfo = (float4*)(ws + 40370176);              // [16384] float4       262144 B
  float*          WgT   = (float*)(ws + 40632320);               // [8][1024] fp32         32768 B

  float* out_logits = out + (size_t)16384 * 1024;
  float* out_sel    = out_logits + (size_t)16384 * 8;
  float* out_w      = out_sel + (size_t)16384 * 2;

  k_transW<<<dim3(18, 16), dim3(256), 0, stream>>>(Wb, B, WcatT);
  k_transA<<<dim3(4, 8), dim3(256), 0, stream>>>(A, AcatT);
  k_transG<<<dim3(4), dim3(256), 0, stream>>>(Wg, WgT);
  k_router<<<dim3(2048), dim3(256), 0, stream>>>(tokens, WgT, out_logits, out_sel, out_w, Xcat, ginfo);
  k_hgemm<<<dim3(512), dim3(256), 0, stream>>>(Xcat, AcatT, ginfo, Xcat);
  k_gemm_main<<<dim3(1024), dim3(256), 0, stream>>>(Xcat, WcatT, out);
}